// Round 4
// baseline (788.799 us; speedup 1.0000x reference)
//
#include <hip/hip_runtime.h>

// ============================================================================
// ViT encoder (patch embed + windowed block + global block) on gfx950.
// Round 10:
//   - mgemm: K-split x2 (blockIdx.z) for the five BN=64 GEMMs -> 768 blocks
//     (3.0 blocks/CU, was 1.5). Linear epilogues via unsafeAtomicAdd into
//     pre-zeroed f32 buffers; z==0 carries bias/pos/res. Final OUT becomes
//     RESA->R0 + cvt_out_k convert.
//   - flash win: K/V stride padded to 256 (VT zeroed via memsetAsync; padded
//     keys masked by j<NT, padded q rows output-guarded) -> uniform tiles,
//     same double-buffered global_load_lds pipeline as the global block.
//   - round-9 swapped-operand softmax, swizzle, literal-base unroll kept.
// ============================================================================

using u16 = unsigned short;
using u32 = unsigned int;
using short8  = __attribute__((ext_vector_type(8))) short;
using floatx4 = __attribute__((ext_vector_type(4))) float;

__device__ __forceinline__ float bfu2f(u16 u) { return __builtin_bit_cast(float, (u32)u << 16); }
__device__ __forceinline__ u16   f2bfu(float f) {
  u32 u = __builtin_bit_cast(u32, f);
  return (u16)((u + 0x7fffu + ((u >> 16) & 1u)) >> 16);   // RNE
}
__device__ __forceinline__ u32 cvtpk_bf16(float a, float b) {   // (lo=a, hi=b), RNE
  u32 r; asm("v_cvt_pk_bf16_f32 %0, %1, %2" : "=v"(r) : "v"(a), "v"(b)); return r;
}
#define DIV14(x) (((x) * 4682) >> 16)   // exact floor(x/14) for 0<=x<256
#define WAIT_VM0()   __builtin_amdgcn_s_waitcnt(0x3f70)   // vmcnt(0)
#define WAIT_LGKM0() __builtin_amdgcn_s_waitcnt(0xc07f)   // lgkmcnt(0)

// async global->LDS, 16B per lane; LDS dest = wave-uniform base + lane*16
__device__ __forceinline__ void gld_lds16(const u16* g, u16* l) {
  __builtin_amdgcn_global_load_lds(
      (const __attribute__((address_space(1))) u32*)g,
      (__attribute__((address_space(3))) u32*)l, 16, 0, 0);
}

// ---------------------------------------------------------------------------
// dtype detector: FLAG=1 => bf16 tensors, FLAG=0 => fp32.
// ---------------------------------------------------------------------------
__global__ __launch_bounds__(256) void detect_k(const u16* __restrict__ x, int* __restrict__ flag)
{
  __shared__ int tot;
  if (threadIdx.x == 0) tot = 0;
  __syncthreads();
  int cnt = 0;
  for (int i = threadIdx.x; i < 4096; i += 256) {
    int e = (x[2 * i] >> 7) & 0xFF;
    cnt += (e >= 100 && e <= 134) ? 1 : 0;
  }
  atomicAdd(&tot, cnt);
  __syncthreads();
  if (threadIdx.x == 0) *flag = (tot >= 2458) ? 1 : 0;
}

// ---------------------------------------------------------------------------
// small-param conversion -> bf16 mirror
// ---------------------------------------------------------------------------
struct CvtEnt { const void* src; int n; int dstoff; };
struct CvtArgs { CvtEnt e[24]; int cnt; };

__global__ __launch_bounds__(256) void tobf_multi_k(CvtArgs a, u16* __restrict__ dst,
                                                    const int* __restrict__ flag)
{
  int gid = blockIdx.x * 256 + threadIdx.x;
  bool isbf = (*flag != 0);
  for (int t = 0; t < a.cnt; ++t)
    if (gid < a.e[t].n)
      dst[a.e[t].dstoff + gid] = isbf ? ((const u16*)a.e[t].src)[gid]
                                      : f2bfu(((const float*)a.e[t].src)[gid]);
}

__global__ __launch_bounds__(256) void tobf4_k(const void* __restrict__ src, u16* __restrict__ dst,
                                               int n4, const int* __restrict__ flag)
{
  int i = blockIdx.x * 256 + threadIdx.x;
  if (i >= n4) return;
  ushort4 o;
  if (*flag) o = ((const ushort4*)src)[i];
  else {
    float4 f = ((const float4*)src)[i];
    o.x = f2bfu(f.x); o.y = f2bfu(f.y); o.z = f2bfu(f.z); o.w = f2bfu(f.w);
  }
  ((ushort4*)dst)[i] = o;
}

// ---------------------------------------------------------------------------
// Final output convert: R0 f32 -> d_out (bf16 or f32 by flag)
// ---------------------------------------------------------------------------
__global__ __launch_bounds__(256) void cvt_out_k(const float* __restrict__ src,
                                                 void* __restrict__ dst,
                                                 const int* __restrict__ flag)
{
  int i = blockIdx.x * 256 + threadIdx.x;
  float4 v = ((const float4*)src)[i];
  if (*flag) {
    ushort4 o;
    o.x = f2bfu(v.x); o.y = f2bfu(v.y); o.z = f2bfu(v.z); o.w = f2bfu(v.w);
    ((ushort4*)dst)[i] = o;
  } else {
    ((float4*)dst)[i] = v;
  }
}

// ---------------------------------------------------------------------------
// Batched weight convert+transpose: W[K][N] -> Wt[N][K] bf16, 64x64 LDS tiles.
// ---------------------------------------------------------------------------
struct TJob { const void* src; int dstoff; int K; int N; int blk0; };
struct TArgs { TJob j[6]; int njobs; };

__global__ __launch_bounds__(256) void tobfT_multi_k(TArgs a, u16* __restrict__ wa,
                                                     const int* __restrict__ flag)
{
  __shared__ u16 t[64][65];
  const int bid = blockIdx.x;
  int ji = 0;
  #pragma unroll
  for (int q = 1; q < 6; ++q) if (q < a.njobs && bid >= a.j[q].blk0) ji = q;
  const void* src = a.j[ji].src;
  u16* dst = wa + a.j[ji].dstoff;
  const int K = a.j[ji].K, N = a.j[ji].N;
  const int local = bid - a.j[ji].blk0;
  const int nx = N >> 6;
  const int bx = local % nx, by = local / nx;
  const int n0 = bx * 64, k0 = by * 64;
  const int r = threadIdx.x >> 2, c = (threadIdx.x & 3) * 16;
  if (*flag) {
    const u16* s = (const u16*)src + (size_t)(k0 + r) * N + n0 + c;
    union { uint4 v[2]; u16 e[16]; } u;
    u.v[0] = *(const uint4*)s; u.v[1] = *(const uint4*)(s + 8);
    #pragma unroll
    for (int j = 0; j < 16; ++j) t[c + j][r] = u.e[j];
  } else {
    const float* s = (const float*)src + (size_t)(k0 + r) * N + n0 + c;
    #pragma unroll
    for (int j = 0; j < 16; ++j) t[c + j][r] = f2bfu(s[j]);
  }
  __syncthreads();
  union { uint4 v[2]; u16 e[16]; } o;
  #pragma unroll
  for (int j = 0; j < 16; ++j) o.e[j] = t[r][c + j];
  u16* d = dst + (size_t)(n0 + r) * K + k0 + c;
  *(uint4*)d = o.v[0]; *(uint4*)(d + 8) = o.v[1];
}

// ---------------------------------------------------------------------------
// im2col for the 16x16/stride-16 patch embed
// ---------------------------------------------------------------------------
__global__ __launch_bounds__(256) void im2col_k(const void* __restrict__ xv, u16* __restrict__ a,
                                                const int* __restrict__ flag)
{
  int t = blockIdx.x, tid = threadIdx.x;
  int py = t >> 6, px = t & 63;
  int ky = tid >> 4, kx = tid & 15;
  size_t src = (size_t)(py * 16 + ky) * 1024 + px * 16 + kx;
  u16 v0, v1, v2;
  if (*flag) {
    const u16* x = (const u16*)xv;
    v0 = x[src]; v1 = x[src + 1048576]; v2 = x[src + 2097152];
  } else {
    const float* x = (const float*)xv;
    v0 = f2bfu(x[src]); v1 = f2bfu(x[src + 1048576]); v2 = f2bfu(x[src + 2097152]);
  }
  size_t dst = (size_t)t * 768 + tid * 3;
  a[dst] = v0; a[dst + 1] = v1; a[dst + 2] = v2;
}

// ---------------------------------------------------------------------------
// LayerNorm over C=768, f32 in -> bf16 out
// ---------------------------------------------------------------------------
__global__ __launch_bounds__(256) void ln_k(const float* __restrict__ x,
                                            const u16* __restrict__ g,
                                            const u16* __restrict__ b,
                                            u16* __restrict__ y)
{
  const int t = blockIdx.x, tid = threadIdx.x;
  const float* xp = x + (size_t)t * 768;
  float v0 = xp[tid], v1 = xp[tid + 256], v2 = xp[tid + 512];
  float s = v0 + v1 + v2;
  float q = v0 * v0 + v1 * v1 + v2 * v2;
  #pragma unroll
  for (int off = 32; off; off >>= 1) { s += __shfl_xor(s, off); q += __shfl_xor(q, off); }
  __shared__ float red[8];
  int wid = tid >> 6, lane = tid & 63;
  if (lane == 0) { red[wid] = s; red[4 + wid] = q; }
  __syncthreads();
  s = red[0] + red[1] + red[2] + red[3];
  q = red[4] + red[5] + red[6] + red[7];
  float mean = s * (1.f / 768.f);
  float var  = q * (1.f / 768.f) - mean * mean;
  float rstd = rsqrtf(var + 1e-5f);
  u16* yp = y + (size_t)t * 768;
  yp[tid]       = f2bfu((v0 - mean) * rstd * bfu2f(g[tid])       + bfu2f(b[tid]));
  yp[tid + 256] = f2bfu((v1 - mean) * rstd * bfu2f(g[tid + 256]) + bfu2f(b[tid + 256]));
  yp[tid + 512] = f2bfu((v2 - mean) * rstd * bfu2f(g[tid + 512]) + bfu2f(b[tid + 512]));
}

// ---------------------------------------------------------------------------
// Fused LayerNorm + window partition: R0 (dense f32) -> Wb (windowed bf16).
// ---------------------------------------------------------------------------
__global__ __launch_bounds__(256) void ln_win_k(const float* __restrict__ x,
                                                const u16* __restrict__ g,
                                                const u16* __restrict__ b,
                                                u16* __restrict__ wout)
{
  const int t = blockIdx.x, tid = threadIdx.x;
  const int win = t / 196, tok = t - win * 196;
  const int ty = DIV14(tok), tx = tok - 14 * ty;
  const int gy = (win / 5) * 14 + ty, gx = (win % 5) * 14 + tx;
  u16* yp = wout + (size_t)t * 768;
  if (gy >= 64 || gx >= 64) {
    yp[tid] = 0; yp[tid + 256] = 0; yp[tid + 512] = 0;
    return;
  }
  const float* xp = x + (size_t)(gy * 64 + gx) * 768;
  float v0 = xp[tid], v1 = xp[tid + 256], v2 = xp[tid + 512];
  float s = v0 + v1 + v2;
  float q = v0 * v0 + v1 * v1 + v2 * v2;
  #pragma unroll
  for (int off = 32; off; off >>= 1) { s += __shfl_xor(s, off); q += __shfl_xor(q, off); }
  __shared__ float red[8];
  int wid = tid >> 6, lane = tid & 63;
  if (lane == 0) { red[wid] = s; red[4 + wid] = q; }
  __syncthreads();
  s = red[0] + red[1] + red[2] + red[3];
  q = red[4] + red[5] + red[6] + red[7];
  float mean = s * (1.f / 768.f);
  float var  = q * (1.f / 768.f) - mean * mean;
  float rstd = rsqrtf(var + 1e-5f);
  yp[tid]       = f2bfu((v0 - mean) * rstd * bfu2f(g[tid])       + bfu2f(b[tid]));
  yp[tid + 256] = f2bfu((v1 - mean) * rstd * bfu2f(g[tid + 256]) + bfu2f(b[tid + 256]));
  yp[tid + 512] = f2bfu((v2 - mean) * rstd * bfu2f(g[tid + 512]) + bfu2f(b[tid + 512]));
}

// ---------------------------------------------------------------------------
// MFMA GEMM, double-buffered global_load_lds staging, optional K-split x2
// (gridDim.z) with atomic f32 accumulation (z==0 carries bias/pos/res).
// ---------------------------------------------------------------------------
enum { MODE_QKV = 1, MODE_GELU = 3, MODE_FEATA = 5, MODE_RESA = 6 };

template<int BN>
__global__ __launch_bounds__(256) void mgemm_k(
    const u16* __restrict__ A, const u16* __restrict__ Bt, const u16* __restrict__ bias,
    int M, int N, int K, int mode,
    float* __restrict__ outf, u16* __restrict__ outb,
    const float* __restrict__ res, const u16* __restrict__ pos,
    u16* __restrict__ qb, u16* __restrict__ kb, u16* __restrict__ vt, int TW, int TP,
    const int* __restrict__ flagp)
{
  constexpr int NWN = BN / 64, NWM = 4 / NWN;
  constexpr int WTM = 128 / NWM;            // 64 or 32
  constexpr int MS = WTM / 16, NS = 4;
  __shared__ __align__(16) u16 As[2][128 * 32];
  __shared__ __align__(16) u16 Bs[2][BN * 32];
  const int tid = threadIdx.x;
  const int wid = tid >> 6, lane = tid & 63;
  const int l15 = lane & 15, quad = lane >> 4;
  const int wm = wid / NWN, wn = wid % NWN;
  const int m0 = blockIdx.y * 128, n0 = blockIdx.x * BN;
  const int nz = (int)gridDim.z;
  const int kloc = K / nz;
  const int kbeg = blockIdx.z * kloc, kend = kbeg + kloc;
  const bool z0 = (blockIdx.z == 0);

  floatx4 acc[MS][NS];
  #pragma unroll
  for (int i = 0; i < MS; ++i)
    #pragma unroll
    for (int j = 0; j < NS; ++j) acc[i][j] = (floatx4){0.f, 0.f, 0.f, 0.f};

  // staging: per wave, 16 rows per DMA call (lane>>2), 8 u16/lane ((lane&3)*8)
  const int sr = lane >> 2, sc = (lane & 3) * 8;
  const u16* ag0 = A + (size_t)min(m0 + wid * 32 + sr,      M - 1) * K + sc;
  const u16* ag1 = A + (size_t)min(m0 + wid * 32 + 16 + sr, M - 1) * K + sc;
  const u16 *bg0 = nullptr, *bg1 = nullptr;
  if constexpr (BN == 128) {
    bg0 = Bt + (size_t)(n0 + wid * 32 + sr) * K + sc;
    bg1 = Bt + (size_t)(n0 + wid * 32 + 16 + sr) * K + sc;
  } else {
    bg0 = Bt + (size_t)(n0 + wid * 16 + sr) * K + sc;
  }

  auto issue = [&](int buf, int k0) {
    gld_lds16(ag0 + k0, &As[buf][(wid * 32) * 32]);
    gld_lds16(ag1 + k0, &As[buf][(wid * 32 + 16) * 32]);
    if constexpr (BN == 128) {
      gld_lds16(bg0 + k0, &Bs[buf][(wid * 32) * 32]);
      gld_lds16(bg1 + k0, &Bs[buf][(wid * 32 + 16) * 32]);
    } else {
      gld_lds16(bg0 + k0, &Bs[buf][(wid * 16) * 32]);
    }
  };

  issue(0, kbeg);
  int bufi = 0;
  for (int k0 = kbeg; k0 < kend; k0 += 32, bufi ^= 1) {
    WAIT_VM0();                 // my DMA for buf bufi landed
    __syncthreads();            // all waves' DMA landed; prior compute done
    if (k0 + 32 < kend) issue(bufi ^ 1, k0 + 32);   // next tile flies during MFMAs
    short8 af[MS], bf[NS];
    #pragma unroll
    for (int ms = 0; ms < MS; ++ms)
      af[ms] = *(const short8*)&As[bufi][(wm * WTM + ms * 16 + l15) * 32 + quad * 8];
    #pragma unroll
    for (int ns = 0; ns < NS; ++ns)
      bf[ns] = *(const short8*)&Bs[bufi][(wn * 64 + ns * 16 + l15) * 32 + quad * 8];
    #pragma unroll
    for (int ms = 0; ms < MS; ++ms)
      #pragma unroll
      for (int ns = 0; ns < NS; ++ns)
        acc[ms][ns] = __builtin_amdgcn_mfma_f32_16x16x32_bf16(af[ms], bf[ns], acc[ms][ns], 0, 0, 0);
  }

  #pragma unroll
  for (int ms = 0; ms < MS; ++ms) {
    const int gmb = m0 + wm * WTM + ms * 16 + quad * 4;
    #pragma unroll
    for (int ns = 0; ns < NS; ++ns) {
      const int gn = n0 + wn * 64 + ns * 16 + l15;
      const float bb = bfu2f(bias[gn]);
      if (mode == MODE_QKV) {
        const int s = gn / 768, nn = gn - s * 768, h = nn >> 6, d = nn & 63;
        #pragma unroll
        for (int r = 0; r < 4; ++r) {
          int gm = gmb + r; if (gm >= M) continue;
          float v = acc[ms][ns][r] + bb;
          int b = gm / TW, tok = gm - b * TW;
          size_t bh = (size_t)(b * 12 + h);
          if (s == 0)      qb[(bh * TP + tok) * 64 + d] = f2bfu(v);
          else if (s == 1) kb[(bh * TP + tok) * 64 + d] = f2bfu(v);
          else             vt[(bh * 64 + d) * TP + tok] = f2bfu(v);
        }
      } else if (mode == MODE_GELU) {
        #pragma unroll
        for (int r = 0; r < 4; ++r) {
          int gm = gmb + r; if (gm >= M) continue;
          size_t o = (size_t)gm * N + gn;
          float v = acc[ms][ns][r] + bb;
          outb[o] = f2bfu(0.5f * v * (1.f + erff(v * 0.70710678f)));
        }
      } else if (mode == MODE_FEATA) {
        #pragma unroll
        for (int r = 0; r < 4; ++r) {
          int gm = gmb + r; if (gm >= M) continue;
          size_t o = (size_t)gm * N + gn;
          float v = acc[ms][ns][r];
          if (z0) v += bb + bfu2f(pos[o]);
          unsafeAtomicAdd(&outf[o], v);
        }
      } else {  // MODE_RESA
        #pragma unroll
        for (int r = 0; r < 4; ++r) {
          int gm = gmb + r; if (gm >= M) continue;
          size_t o = (size_t)gm * N + gn;
          float v = acc[ms][ns][r];
          if (z0) v += bb + res[o];
          unsafeAtomicAdd(&outf[o], v);
        }
      }
    }
  }
}

// ---------------------------------------------------------------------------
// MFMA flash attention, swapped-operand (lane-local softmax rows).
// NT = logical tokens, NTP = padded stride (multiple of 64). Both WIN and
// !WIN use double-buffered global_load_lds K/V staging with pre-swizzled
// per-lane sources; K-loop unrolled x2 with literal dbuf bases. Padded keys
// masked via j<NT (WIN); padded V rows are pre-zeroed in global memory.
// ---------------------------------------------------------------------------
template<int NT, int NTP, int TD, bool WIN>
__global__ __launch_bounds__(256) void flash_k(
    const u16* __restrict__ qb, const u16* __restrict__ kb, const u16* __restrict__ vt,
    const u16* __restrict__ relh, const u16* __restrict__ relw,
    u16* __restrict__ outb)
{
  constexpr int NTAB = 2 * TD - 1;
  constexpr int KT = NTP >> 6;
  constexpr float L2E = 1.4426950408889634f;
  constexpr float SC2 = 0.125f * L2E;
  // swizzled 64x64 u16 tile regions (4096 u16 each)
  constexpr int RQ  = 0;                          // Q stage -> P
  constexpr int RK0 = 4096;                       // K buf0; !WIN pre-loop: GW scratch
  constexpr int RK1 = 8192;                       // K buf1
  constexpr int RV0 = 12288;                      // V buf0; pre-loop: rel staging
  constexpr int RV1 = 16384;                      // V buf1
  constexpr int RG  = 20480;                      // GH table
  constexpr int GWWIN = RG + 64 * 34;
  constexpr int TOT = WIN ? (GWWIN + 64 * 34) : (RG + 64 * 66);
  __shared__ __align__(16) u16 lds[TOT];

  const int tid = threadIdx.x, wid = tid >> 6, lane = tid & 63;
  const int l15 = lane & 15, quad = lane >> 4;
  const int qt = blockIdx.x, bh = blockIdx.y;
  const int q0 = qt * 64;
  const size_t kvbase = (size_t)bh * NTP * 64;
  const size_t vbase  = (size_t)bh * 64 * NTP;
  const int myrow = wid * 16 + l15;               // this lane's q-row (lane-const)

  // u16 index of 16B block blk (0..7) in swizzled row
  auto swb = [](int row, int blk) { return row * 64 + (((blk ^ row) & 7) << 3); };

  // ---- stage Q tile (swizzled), hoist fragment to VGPRs ----
  {
    const int r = tid >> 2, cb = (tid & 3) * 2;
    const int tok = WIN ? (q0 + r) : min(q0 + r, NT - 1);
    const uint4* p = (const uint4*)(qb + kvbase + (size_t)tok * 64 + cb * 8);
    *(uint4*)&lds[RQ + swb(r, cb)]     = p[0];
    *(uint4*)&lds[RQ + swb(r, cb + 1)] = p[1];
  }
  __syncthreads();
  short8 qf[2];
  qf[0] = *(const short8*)&lds[RQ + swb(myrow, quad)];
  qf[1] = *(const short8*)&lds[RQ + swb(myrow, 4 + quad)];
  WAIT_LGKM0();   // Q reads done before anything (later P writes) touch RQ

  auto stageRB = [&](const u16* tab, int rowoff, int maxrow) {
    const int r = tid >> 2, cb = (tid & 3) * 2;
    const int tr = min(rowoff + r, maxrow);
    const uint4* p = (const uint4*)(tab + (size_t)tr * 64 + cb * 8);
    *(uint4*)&lds[RV0 + swb(r, cb)]     = p[0];
    *(uint4*)&lds[RV0 + swb(r, cb + 1)] = p[1];
  };
  auto gpass = [&](int gbase, int gstride, int ncols) {
    for (int ns = 0; ns < ncols / 16; ++ns) {
      floatx4 g = (floatx4){0.f, 0.f, 0.f, 0.f};
      #pragma unroll
      for (int ks = 0; ks < 2; ++ks) {
        short8 b = *(const short8*)&lds[RV0 + swb(ns * 16 + l15, ks * 4 + quad)];
        g = __builtin_amdgcn_mfma_f32_16x16x32_bf16(qf[ks], b, g, 0, 0, 0);
      }
      #pragma unroll
      for (int r = 0; r < 4; ++r)
        lds[gbase + (wid * 16 + quad * 4 + r) * gstride + ns * 16 + l15] = f2bfu(g[r] * L2E);
    }
  };

  // gwv[kbi][r]: GW bias for key = kbi*16 + quad*4 + r of this lane's row
  float gwv[4][4];
  if constexpr (!WIN) {
    stageRB(relh, qt, NTAB - 1);  __syncthreads();
    gpass(RG, 66, 64);                            // GH
    __syncthreads();                              // RV0 reads done -> restage ok
    stageRB(relw, 0, NTAB - 1);   __syncthreads();
    gpass(RK0, 66, 64);                           // GW cols 0..63 (scratch in K region)
    #pragma unroll
    for (int kbi = 0; kbi < 4; ++kbi)
      #pragma unroll
      for (int r = 0; r < 4; ++r) {
        const int iw = myrow + 63 - (kbi * 16 + quad * 4 + r);
        if (iw < 64) gwv[kbi][r] = bfu2f(lds[RK0 + myrow * 66 + iw]);
      }
    WAIT_LGKM0();
    __syncthreads();                              // scratch reads done -> restage ok
    stageRB(relw, 64, NTAB - 1);  __syncthreads();
    gpass(RK0, 66, 64);                           // GW cols 64..126 (stored 0..62)
    #pragma unroll
    for (int kbi = 0; kbi < 4; ++kbi)
      #pragma unroll
      for (int r = 0; r < 4; ++r) {
        const int iw = myrow + 63 - (kbi * 16 + quad * 4 + r);
        if (iw >= 64) gwv[kbi][r] = bfu2f(lds[RK0 + myrow * 66 + iw - 64]);
      }
    WAIT_LGKM0();   // GW reads done before DMA overwrites the K region
  } else {
    stageRB(relh, 0, NTAB - 1);  __syncthreads();
    gpass(RG, 34, 32);
    __syncthreads();
    stageRB(relw, 0, NTAB - 1);  __syncthreads();
    gpass(GWWIN, 34, 32);
  }

  // ---- double-buffered DMA staging, stepped pre-swizzled pointers ----
  const int srow = lane >> 3;
  const int scol = (((lane & 7) ^ srow) & 7) << 3;
  const u16* kp  = kb + kvbase + (size_t)(wid * 16 + srow) * 64 + scol;
  const u16* kp2 = kp + 512;                      // +8 key rows
  const u16* vp  = vt + vbase  + (size_t)(wid * 16 + srow) * NTP + scol;
  const u16* vp2 = vp + (size_t)8 * NTP;          // +8 d rows
  u16* const kd0 = &lds[RK0 + wid * 1024];
  u16* const kd1 = &lds[RK1 + wid * 1024];
  u16* const vd0 = &lds[RV0 + wid * 1024];
  u16* const vd1 = &lds[RV1 + wid * 1024];
  auto issueKV = [&](int buf) {
    u16* kdb = buf ? kd1 : kd0;
    u16* vdb = buf ? vd1 : vd0;
    gld_lds16(kp,  kdb);
    gld_lds16(kp2, kdb + 512);
    gld_lds16(vp,  vdb);
    gld_lds16(vp2, vdb + 512);
    kp += 4096; kp2 += 4096; vp += 64; vp2 += 64;
  };

  // ---- per-lane online-softmax state (row = myrow), exp2 domain ----
  float mI = -3e38f, lI = 0.f;
  floatx4 Oacc[4];                                // Oacc[dblk]: rows d, col = myrow
  #pragma unroll
  for (int d = 0; d < 4; ++d) Oacc[d] = (floatx4){0.f, 0.f, 0.f, 0.f};

  // WIN: per-lane q coords (lane-const)
  int qy = 0, qx = 0;
  if constexpr (WIN) {
    const int tok0 = q0 + myrow;
    qy = DIV14(tok0); qx = tok0 - 14 * qy;
  }

  // ---- shared per-tile body (inlined; bases literal at call sites) ----
  auto body = [&](int RKb, int RVb, int kt) {
    // QK^T swapped: C[key][q], lane col = myrow
    floatx4 sacc[4];
    #pragma unroll
    for (int kbi = 0; kbi < 4; ++kbi) sacc[kbi] = (floatx4){0.f, 0.f, 0.f, 0.f};
    __builtin_amdgcn_s_setprio(1);
    #pragma unroll
    for (int ks = 0; ks < 2; ++ks)
      #pragma unroll
      for (int kbi = 0; kbi < 4; ++kbi) {
        short8 a = *(const short8*)&lds[RKb + swb(kbi * 16 + l15, ks * 4 + quad)];
        sacc[kbi] = __builtin_amdgcn_mfma_f32_16x16x32_bf16(a, qf[ks], sacc[kbi], 0, 0, 0);
      }
    __builtin_amdgcn_s_setprio(0);

    // scale + rel bias (log2 units); sv[kbi][r] = score for key kbi*16+quad*4+r
    float sv[4][4];
    if constexpr (!WIN) {
      #pragma unroll
      for (int kbi = 0; kbi < 4; ++kbi)
        #pragma unroll
        for (int r = 0; r < 4; ++r)
          sv[kbi][r] = fmaf(SC2, sacc[kbi][r], gwv[kbi][r]);   // Gh folded below
    } else {
      #pragma unroll
      for (int kbi = 0; kbi < 4; ++kbi)
        #pragma unroll
        for (int r = 0; r < 4; ++r) {
          const int j = kt * 64 + kbi * 16 + quad * 4 + r;
          const int ky = DIV14(j), kx = j - 14 * ky;
          int ih = qy - ky + 13; ih = max(0, min(ih, 31));
          int iw = qx - kx + 13; iw = max(0, min(iw, 31));
          float s = SC2 * sacc[kbi][r] + bfu2f(lds[RG + myrow * 34 + ih])
                                       + bfu2f(lds[GWWIN + myrow * 34 + iw]);
          sv[kbi][r] = (j < NT) ? s : -1e30f;
        }
    }

    // row reduce: in-lane tree + 2 cross-quad shuffles
    float rm;
    {
      float a0 = fmaxf(fmaxf(sv[0][0], sv[0][1]), fmaxf(sv[0][2], sv[0][3]));
      float a1 = fmaxf(fmaxf(sv[1][0], sv[1][1]), fmaxf(sv[1][2], sv[1][3]));
      float a2 = fmaxf(fmaxf(sv[2][0], sv[2][1]), fmaxf(sv[2][2], sv[2][3]));
      float a3 = fmaxf(fmaxf(sv[3][0], sv[3][1]), fmaxf(sv[3][2], sv[3][3]));
      rm = fmaxf(fmaxf(a0, a1), fmaxf(a2, a3));
    }
    rm = fmaxf(rm, __shfl_xor(rm, 16));
    rm = fmaxf(rm, __shfl_xor(rm, 32));
    float ghv = 0.f;
    if constexpr (!WIN) ghv = bfu2f(lds[RG + myrow * 66 + (63 - kt)]);   // tile-const
    const float mt = rm + ghv;
    const float mn = fmaxf(mI, mt);
    const float tt = mn - ghv;

    float rs = 0.f;
    u32 pk[8];
    #pragma unroll
    for (int kbi = 0; kbi < 4; ++kbi) {
      float p0 = __builtin_amdgcn_exp2f(sv[kbi][0] - tt);
      float p1 = __builtin_amdgcn_exp2f(sv[kbi][1] - tt);
      float p2 = __builtin_amdgcn_exp2f(sv[kbi][2] - tt);
      float p3 = __builtin_amdgcn_exp2f(sv[kbi][3] - tt);
      rs += (p0 + p1) + (p2 + p3);
      pk[2 * kbi]     = cvtpk_bf16(p0, p1);
      pk[2 * kbi + 1] = cvtpk_bf16(p2, p3);
    }

    // write P: row myrow, cols kbi*16+quad*4 .. +3 (one b64 per kbi)
    #pragma unroll
    for (int kbi = 0; kbi < 4; ++kbi) {
      const int col = kbi * 16 + quad * 4;
      uint2 w2; w2.x = pk[2 * kbi]; w2.y = pk[2 * kbi + 1];
      *(uint2*)&lds[RQ + myrow * 64 + ((((col >> 3) ^ myrow) & 7) << 3) + (col & 7)] = w2;
    }

    // al == 1.0 exactly when no lane saw a new max -> lI update bit-exact
    const float al = __builtin_amdgcn_exp2f(mI - mn);
    if (__any(mt > mI)) {
      #pragma unroll
      for (int d = 0; d < 4; ++d) Oacc[d] *= al;
    }
    mI = mn;

    // PV swapped: A = V-frag (rows d), B = P-frag (col = myrow) -> O^T
    __builtin_amdgcn_s_setprio(1);
    #pragma unroll
    for (int ks = 0; ks < 2; ++ks) {
      short8 pb = *(const short8*)&lds[RQ + swb(myrow, ks * 4 + quad)];
      #pragma unroll
      for (int d = 0; d < 4; ++d) {
        short8 a = *(const short8*)&lds[RVb + swb(d * 16 + l15, ks * 4 + quad)];
        Oacc[d] = __builtin_amdgcn_mfma_f32_16x16x32_bf16(a, pb, Oacc[d], 0, 0, 0);
      }
    }
    __builtin_amdgcn_s_setprio(0);

    // rs cross-lane reduce hidden under PV MFMAs
    rs += __shfl_xor(rs, 16);
    rs += __shfl_xor(rs, 32);
    lI = fmaf(lI, al, rs);
  };

  // ---- K loop (KT even for both paths) ----
  __syncthreads();              // all waves done with pre-loop LDS scratch
  issueKV(0);                   // tile 0 -> buf0
  for (int kt = 0; kt < KT; kt += 2) {
    WAIT_VM0();                 // my DMA for tile kt landed
    __syncthreads();            // all waves' DMA landed; prior reads done
    if (kt + 1 < KT) issueKV(1);
    body(RK0, RV0, kt);
    WAIT_VM0();                 // my DMA for tile kt+1 landed
    __syncthreads();
    if (kt + 2 < KT) issueKV(0);
    body(RK1, RV1, kt + 1);
  }

  // ---- output: O^T rows d = dblk*16+quad*4+r, col = myrow (= token) ----
  const float rinv = 1.f / lI;
  const int tok = q0 + myrow;
  u32 ow[8];
  #pragma unroll
  for (int d = 0; d < 4; ++d) {
    ow[2 * d]     = cvtpk_bf16(Oacc[d][0] * rinv, Oacc[d][1] * rinv);
    ow[2 * d + 1] = cvtpk_bf16(Oacc[d][2] * rinv, Oacc[d][3] * rinv);
  }
  if constexpr (WIN) {
    if (tok < NT) {
      const int win = bh / 12, h = bh - win * 12;
      const int ty = DIV14(tok), tx = tok - 14 * ty;
      const int gy = (win / 5) * 14 + ty, gx = (win % 5) * 14 + tx;
      if (gy < 64 && gx < 64) {
        u16* op = outb + (size_t)(gy * 64 + gx) * 768 + h * 64;
        #pragma unroll
        for (int d = 0; d < 4; ++d)
          *(uint2*)(op + d * 16 + quad * 4) = make_uint2(ow[2 * d], ow[2 * d + 1]);
      }
    }
  } else {
    u16* op = outb + (size_t)tok * 768 + bh * 64;
    #pragma unroll
    for (int d = 0; d < 4; ++d)
      *(uint2*)(op + d * 16 + quad * 4) = make_uint2(ow[2 * d], ow[2 * d + 1]);
  }
}

// ---------------------------------------------------------------------------
extern "C" void kernel_launch(void* const* d_in, const int* in_sizes, int n_in,
                              void* d_out, int out_size, void* d_ws, size_t ws_size,
                              hipStream_t stream)
{
  const void* x      = d_in[0];
  const void* patchw = d_in[1];
  const void* patchb = d_in[2];
  const void* pos    = d_in[3];
  const void *ln1g1 = d_in[4],  *ln1b1 = d_in[5];
  const void *qkvw1 = d_in[6],  *qkvb1 = d_in[7];
  const void *projw1= d_in[8],  *projb1= d_in[9];
  const void *relh1 = d_in[10], *relw1 = d_in[11];
  const void *ln2g1 = d_in[12], *ln2b1 = d_in[13];
  const void *mw11  = d_in[14], *mb11  = d_in[15];
  const void *mw21  = d_in[16], *mb21  = d_in[17];
  const void *ln1g2 = d_in[18], *ln1b2 = d_in[19];
  const void *qkvw2 = d_in[20], *qkvb2 = d_in[21];
  const void *projw2= d_in[22], *projb2= d_in[23];
  const void *relh2 = d_in[24], *relw2 = d_in[25];
  const void *ln2g2 = d_in[26], *ln2b2 = d_in[27];
  const void *mw12  = d_in[28], *mb12  = d_in[29];
  const void *mw22  = d_in[30], *mb22  = d_in[31];

  char* w = (char*)d_ws;
  int*   FLAG = (int*)w;  w += 64;
  float* R0 = (float*)w;  w += 12582912;
  float* R1 = (float*)w;  w += 12582912;
  u16*   B0 = (u16*)w;    w += 6291456;
  u16*   Wb = (u16*)w;    w += 7526400;
  u16*   QB = (u16*)w;    w += 9830400;   // [bh][tok][64], padded tok stride
  u16*   KB = (u16*)w;    w += 9830400;   // [bh][tok][64]
  u16*   VT = (u16*)w;    w += 9830400;   // [bh][d][tok]
  u16*   Hb = (u16*)w;    w += 25165824;
  u16*   WA = (u16*)w;    w += 15335424;  // transposed weight arena (+patch slot)
  u16*   POSb = (u16*)w;  w += 6291456;
  u16*   PRM = (u16*)w;   w += 106560;
  u16*   Ap = Hb;

  constexpr int WA_QKV = 0, WA_PROJ = 1769472, WA_M1 = 2359296, WA_M2 = 4718592,
                WA_PATCH = 7077888;
  constexpr int PRM_PATCHB = 0, PB1 = 768, PBLK = 26240, PB2 = 768 + PBLK;
  constexpr int O_QKVB = 0, O_PROJB = 2304, O_MB1 = 3072, O_MB2 = 6144,
                O_LN1G = 6912, O_LN1B = 7680, O_LN2G = 8448, O_LN2B = 9216,
                O_RELH = 9984, O_RELW = 18112;

  detect_k<<<1, 256, 0, stream>>>((const u16*)x, FLAG);
  CvtArgs ca; int kk = 0;
  auto add = [&](const void* s, int n, int off) { ca.e[kk].src = s; ca.e[kk].n = n; ca.e[kk].dstoff = off; ++kk; };
  add(patchb, 768, PRM_PATCHB);
  add(qkvb1, 2304, PB1 + O_QKVB); add(projb1, 768, PB1 + O_PROJB);
  add(mb11, 3072, PB1 + O_MB1);   add(mb21, 768, PB1 + O_MB2);
  add(ln1g1, 768, PB1 + O_LN1G);  add(ln1b1, 768, PB1 + O_LN1B);
  add(ln2g1, 768, PB1 + O_LN2G);  add(ln2b1, 768, PB1 + O_LN2B);
  add(relh1, 27 * 64, PB1 + O_RELH); add(relw1, 27 * 64, PB1 + O_RELW);
  add(qkvb2, 2304, PB2 + O_QKVB); add(projb2, 768, PB2 + O_PROJB);
  add(mb12, 3072, PB2 + O_MB1);   add(mb22, 768, PB2 + O_MB2);
  add(ln1g2, 768, PB2 + O_LN1G);  add(ln1b2, 768, PB2 + O_LN1B);
  add(ln2g2, 768, PB2 + O_LN2G);  add(ln2b2, 768, PB2 + O_LN2B);
  add(relh2, 127 * 64, PB2 + O_RELH); add(relw2, 127 * 64, PB2 + O_RELW);
  ca.cnt = kk;
  tobf_multi_k<<<32, 256, 0, stream>>>(ca, PRM, FLAG);
  tobf4_k<<<3072, 256, 0, stream>>>(pos, POSb, 786432, FLAG);

  // ---- fused weight transposes: set 1 (patch + block 1) ----
  {
    TArgs ta; int nb = 0, jn = 0;
    auto addT = [&](const void* s, int dstoff, int K, int N) {
      ta.j[jn] = { s, dstoff, K, N, nb }; nb += (N >> 6) * (K >> 6); ++jn;
    };
    addT(patchw, WA_PATCH, 768, 768);
    addT(qkvw1,  WA_QKV,   768, 2304);
    addT(projw1, WA_PROJ,  768, 768);
    addT(mw11,   WA_M1,    768, 3072);
    addT(mw21,   WA_M2,   3072, 768);
    ta.njobs = jn;
    tobfT_multi_k<<<nb, 256, 0, stream>>>(ta, WA, FLAG);
  }

  // ---- patch embed ----
  im2col_k<<<4096, 256, 0, stream>>>(x, Ap, FLAG);
  hipMemsetAsync(R0, 0, 12582912, stream);
  mgemm_k<64><<<dim3(12, 32, 2), 256, 0, stream>>>(Ap, WA + WA_PATCH, PRM + PRM_PATCHB,
      4096, 768, 768, MODE_FEATA, R0, nullptr, nullptr, POSb, nullptr, nullptr, nullptr, 0, 0, FLAG);

  // ---- block 1 (windowed) ----
  ln_win_k<<<4900, 256, 0, stream>>>(R0, PRM + PB1 + O_LN1G, PRM + PB1 + O_LN1B, Wb);
  hipMemsetAsync(VT, 0, 9830400, stream);   // padded V cols must be 0 (NaN guard)
  mgemm_k<128><<<dim3(18, 39), 256, 0, stream>>>(Wb, WA + WA_QKV, PRM + PB1 + O_QKVB,
      4900, 2304, 768, MODE_QKV, nullptr, nullptr, nullptr, nullptr, QB, KB, VT, 196, 256, FLAG);
  flash_k<196, 256, 14, true><<<dim3(4, 300), 256, 0, stream>>>(QB, KB, VT,
      PRM + PB1 + O_RELH, PRM + PB1 + O_RELW, B0);
  hipMemsetAsync(R1, 0, 12582912, stream);
  mgemm_k<64><<<dim3(12, 32, 2), 256, 0, stream>>>(B0, WA + WA_PROJ, PRM + PB1 + O_PROJB,
      4096, 768, 768, MODE_RESA, R1, nullptr, R0, nullptr, nullptr, nullptr, nullptr, 0, 0, FLAG);
  ln_k<<<4096, 256, 0, stream>>>(R1, PRM + PB1 + O_LN2G, PRM + PB1 + O_LN2B, B0);
  mgemm_k<128><<<dim3(24, 32), 256, 0, stream>>>(B0, WA + WA_M1, PRM + PB1 + O_MB1,
      4096, 3072, 768, MODE_GELU, nullptr, Hb, nullptr, nullptr, nullptr, nullptr, nullptr, 0, 0, FLAG);
  hipMemsetAsync(R0, 0, 12582912, stream);
  mgemm_k<64><<<dim3(12, 32, 2), 256, 0, stream>>>(Hb, WA + WA_M2, PRM + PB1 + O_MB2,
      4096, 768, 3072, MODE_RESA, R0, nullptr, R1, nullptr, nullptr, nullptr, nullptr, 0, 0, FLAG);

  // ---- fused weight transposes: set 2 (block 2) ----
  {
    TArgs ta; int nb = 0, jn = 0;
    auto addT = [&](const void* s, int dstoff, int K, int N) {
      ta.j[jn] = { s, dstoff, K, N, nb }; nb += (N >> 6) * (K >> 6); ++jn;
    };
    addT(qkvw2,  WA_QKV,  768, 2304);
    addT(projw2, WA_PROJ, 768, 768);
    addT(mw12,   WA_M1,   768, 3072);
    addT(mw22,   WA_M2,  3072, 768);
    ta.njobs = jn;
    tobfT_multi_k<<<nb, 256, 0, stream>>>(ta, WA, FLAG);
  }

  // ---- block 2 (global) ----
  ln_k<<<4096, 256, 0, stream>>>(R0, PRM + PB2 + O_LN1G, PRM + PB2 + O_LN1B, B0);
  mgemm_k<128><<<dim3(18, 32), 256, 0, stream>>>(B0, WA + WA_QKV, PRM + PB2 + O_QKVB,
      4096, 2304, 768, MODE_QKV, nullptr, nullptr, nullptr, nullptr, QB, KB, VT, 4096, 4096, FLAG);
  flash_k<4096, 4096, 64, false><<<dim3(64, 12), 256, 0, stream>>>(QB, KB, VT,
      PRM + PB2 + O_RELH, PRM + PB2 + O_RELW, B0);
  hipMemsetAsync(R1, 0, 12582912, stream);
  mgemm_k<64><<<dim3(12, 32, 2), 256, 0, stream>>>(B0, WA + WA_PROJ, PRM + PB2 + O_PROJB,
      4096, 768, 768, MODE_RESA, R1, nullptr, R0, nullptr, nullptr, nullptr, nullptr, 0, 0, FLAG);
  ln_k<<<4096, 256, 0, stream>>>(R1, PRM + PB2 + O_LN2G, PRM + PB2 + O_LN2B, B0);
  mgemm_k<128><<<dim3(24, 32), 256, 0, stream>>>(B0, WA + WA_M1, PRM + PB2 + O_MB1,
      4096, 3072, 768, MODE_GELU, nullptr, Hb, nullptr, nullptr, nullptr, nullptr, nullptr, 0, 0, FLAG);
  hipMemsetAsync(R0, 0, 12582912, stream);
  mgemm_k<64><<<dim3(12, 32, 2), 256, 0, stream>>>(Hb, WA + WA_M2, PRM + PB2 + O_MB2,
      4096, 768, 3072, MODE_RESA, R0, nullptr, R1, nullptr, nullptr, nullptr, nullptr, 0, 0, FLAG);
  cvt_out_k<<<3072, 256, 0, stream>>>(R0, d_out, FLAG);
}

// Round 5
// 712.647 us; speedup vs baseline: 1.1069x; 1.1069x over previous
//
#include <hip/hip_runtime.h>

// ============================================================================
// ViT encoder (patch embed + windowed block + global block) on gfx950.
// Round 11:
//   - NEW mgemm64_k: BM=BN=BK=64 tile, 4 waves (16x64 out each), XOR-swizzled
//     LDS (blk^=row&7, 2-way max) with pre-swizzled DMA sources, dbuf, one
//     barrier per 64-K. Used for the five M=4096/N=768 GEMMs -> 768 blocks
//     (3 blocks/CU, was 1.5) with DIRECT writes (no atomics/memsets: R4's
//     +50us overhead removed).
//   - mgemm_k<128> unchanged for qkv/gelu (healthy MFMA density).
//   - flash: R4 structure kept (padded TP=256 win path, swapped-operand
//     softmax, literal-base unroll, dbuf DMA).
// ============================================================================

using u16 = unsigned short;
using u32 = unsigned int;
using short8  = __attribute__((ext_vector_type(8))) short;
using floatx4 = __attribute__((ext_vector_type(4))) float;

__device__ __forceinline__ float bfu2f(u16 u) { return __builtin_bit_cast(float, (u32)u << 16); }
__device__ __forceinline__ u16   f2bfu(float f) {
  u32 u = __builtin_bit_cast(u32, f);
  return (u16)((u + 0x7fffu + ((u >> 16) & 1u)) >> 16);   // RNE
}
__device__ __forceinline__ u32 cvtpk_bf16(float a, float b) {   // (lo=a, hi=b), RNE
  u32 r; asm("v_cvt_pk_bf16_f32 %0, %1, %2" : "=v"(r) : "v"(a), "v"(b)); return r;
}
#define DIV14(x) (((x) * 4682) >> 16)   // exact floor(x/14) for 0<=x<256
#define WAIT_VM0()   __builtin_amdgcn_s_waitcnt(0x3f70)   // vmcnt(0)
#define WAIT_LGKM0() __builtin_amdgcn_s_waitcnt(0xc07f)   // lgkmcnt(0)

// async global->LDS, 16B per lane; LDS dest = wave-uniform base + lane*16
__device__ __forceinline__ void gld_lds16(const u16* g, u16* l) {
  __builtin_amdgcn_global_load_lds(
      (const __attribute__((address_space(1))) u32*)g,
      (__attribute__((address_space(3))) u32*)l, 16, 0, 0);
}

// ---------------------------------------------------------------------------
// dtype detector: FLAG=1 => bf16 tensors, FLAG=0 => fp32.
// ---------------------------------------------------------------------------
__global__ __launch_bounds__(256) void detect_k(const u16* __restrict__ x, int* __restrict__ flag)
{
  __shared__ int tot;
  if (threadIdx.x == 0) tot = 0;
  __syncthreads();
  int cnt = 0;
  for (int i = threadIdx.x; i < 4096; i += 256) {
    int e = (x[2 * i] >> 7) & 0xFF;
    cnt += (e >= 100 && e <= 134) ? 1 : 0;
  }
  atomicAdd(&tot, cnt);
  __syncthreads();
  if (threadIdx.x == 0) *flag = (tot >= 2458) ? 1 : 0;
}

// ---------------------------------------------------------------------------
// small-param conversion -> bf16 mirror
// ---------------------------------------------------------------------------
struct CvtEnt { const void* src; int n; int dstoff; };
struct CvtArgs { CvtEnt e[24]; int cnt; };

__global__ __launch_bounds__(256) void tobf_multi_k(CvtArgs a, u16* __restrict__ dst,
                                                    const int* __restrict__ flag)
{
  int gid = blockIdx.x * 256 + threadIdx.x;
  bool isbf = (*flag != 0);
  for (int t = 0; t < a.cnt; ++t)
    if (gid < a.e[t].n)
      dst[a.e[t].dstoff + gid] = isbf ? ((const u16*)a.e[t].src)[gid]
                                      : f2bfu(((const float*)a.e[t].src)[gid]);
}

__global__ __launch_bounds__(256) void tobf4_k(const void* __restrict__ src, u16* __restrict__ dst,
                                               int n4, const int* __restrict__ flag)
{
  int i = blockIdx.x * 256 + threadIdx.x;
  if (i >= n4) return;
  ushort4 o;
  if (*flag) o = ((const ushort4*)src)[i];
  else {
    float4 f = ((const float4*)src)[i];
    o.x = f2bfu(f.x); o.y = f2bfu(f.y); o.z = f2bfu(f.z); o.w = f2bfu(f.w);
  }
  ((ushort4*)dst)[i] = o;
}

// ---------------------------------------------------------------------------
// Batched weight convert+transpose: W[K][N] -> Wt[N][K] bf16, 64x64 LDS tiles.
// ---------------------------------------------------------------------------
struct TJob { const void* src; int dstoff; int K; int N; int blk0; };
struct TArgs { TJob j[6]; int njobs; };

__global__ __launch_bounds__(256) void tobfT_multi_k(TArgs a, u16* __restrict__ wa,
                                                     const int* __restrict__ flag)
{
  __shared__ u16 t[64][65];
  const int bid = blockIdx.x;
  int ji = 0;
  #pragma unroll
  for (int q = 1; q < 6; ++q) if (q < a.njobs && bid >= a.j[q].blk0) ji = q;
  const void* src = a.j[ji].src;
  u16* dst = wa + a.j[ji].dstoff;
  const int K = a.j[ji].K, N = a.j[ji].N;
  const int local = bid - a.j[ji].blk0;
  const int nx = N >> 6;
  const int bx = local % nx, by = local / nx;
  const int n0 = bx * 64, k0 = by * 64;
  const int r = threadIdx.x >> 2, c = (threadIdx.x & 3) * 16;
  if (*flag) {
    const u16* s = (const u16*)src + (size_t)(k0 + r) * N + n0 + c;
    union { uint4 v[2]; u16 e[16]; } u;
    u.v[0] = *(const uint4*)s; u.v[1] = *(const uint4*)(s + 8);
    #pragma unroll
    for (int j = 0; j < 16; ++j) t[c + j][r] = u.e[j];
  } else {
    const float* s = (const float*)src + (size_t)(k0 + r) * N + n0 + c;
    #pragma unroll
    for (int j = 0; j < 16; ++j) t[c + j][r] = f2bfu(s[j]);
  }
  __syncthreads();
  union { uint4 v[2]; u16 e[16]; } o;
  #pragma unroll
  for (int j = 0; j < 16; ++j) o.e[j] = t[r][c + j];
  u16* d = dst + (size_t)(n0 + r) * K + k0 + c;
  *(uint4*)d = o.v[0]; *(uint4*)(d + 8) = o.v[1];
}

// ---------------------------------------------------------------------------
// im2col for the 16x16/stride-16 patch embed
// ---------------------------------------------------------------------------
__global__ __launch_bounds__(256) void im2col_k(const void* __restrict__ xv, u16* __restrict__ a,
                                                const int* __restrict__ flag)
{
  int t = blockIdx.x, tid = threadIdx.x;
  int py = t >> 6, px = t & 63;
  int ky = tid >> 4, kx = tid & 15;
  size_t src = (size_t)(py * 16 + ky) * 1024 + px * 16 + kx;
  u16 v0, v1, v2;
  if (*flag) {
    const u16* x = (const u16*)xv;
    v0 = x[src]; v1 = x[src + 1048576]; v2 = x[src + 2097152];
  } else {
    const float* x = (const float*)xv;
    v0 = f2bfu(x[src]); v1 = f2bfu(x[src + 1048576]); v2 = f2bfu(x[src + 2097152]);
  }
  size_t dst = (size_t)t * 768 + tid * 3;
  a[dst] = v0; a[dst + 1] = v1; a[dst + 2] = v2;
}

// ---------------------------------------------------------------------------
// LayerNorm over C=768, f32 in -> bf16 out
// ---------------------------------------------------------------------------
__global__ __launch_bounds__(256) void ln_k(const float* __restrict__ x,
                                            const u16* __restrict__ g,
                                            const u16* __restrict__ b,
                                            u16* __restrict__ y)
{
  const int t = blockIdx.x, tid = threadIdx.x;
  const float* xp = x + (size_t)t * 768;
  float v0 = xp[tid], v1 = xp[tid + 256], v2 = xp[tid + 512];
  float s = v0 + v1 + v2;
  float q = v0 * v0 + v1 * v1 + v2 * v2;
  #pragma unroll
  for (int off = 32; off; off >>= 1) { s += __shfl_xor(s, off); q += __shfl_xor(q, off); }
  __shared__ float red[8];
  int wid = tid >> 6, lane = tid & 63;
  if (lane == 0) { red[wid] = s; red[4 + wid] = q; }
  __syncthreads();
  s = red[0] + red[1] + red[2] + red[3];
  q = red[4] + red[5] + red[6] + red[7];
  float mean = s * (1.f / 768.f);
  float var  = q * (1.f / 768.f) - mean * mean;
  float rstd = rsqrtf(var + 1e-5f);
  u16* yp = y + (size_t)t * 768;
  yp[tid]       = f2bfu((v0 - mean) * rstd * bfu2f(g[tid])       + bfu2f(b[tid]));
  yp[tid + 256] = f2bfu((v1 - mean) * rstd * bfu2f(g[tid + 256]) + bfu2f(b[tid + 256]));
  yp[tid + 512] = f2bfu((v2 - mean) * rstd * bfu2f(g[tid + 512]) + bfu2f(b[tid + 512]));
}

// ---------------------------------------------------------------------------
// Fused LayerNorm + window partition: R0 (dense f32) -> Wb (windowed bf16).
// ---------------------------------------------------------------------------
__global__ __launch_bounds__(256) void ln_win_k(const float* __restrict__ x,
                                                const u16* __restrict__ g,
                                                const u16* __restrict__ b,
                                                u16* __restrict__ wout)
{
  const int t = blockIdx.x, tid = threadIdx.x;
  const int win = t / 196, tok = t - win * 196;
  const int ty = DIV14(tok), tx = tok - 14 * ty;
  const int gy = (win / 5) * 14 + ty, gx = (win % 5) * 14 + tx;
  u16* yp = wout + (size_t)t * 768;
  if (gy >= 64 || gx >= 64) {
    yp[tid] = 0; yp[tid + 256] = 0; yp[tid + 512] = 0;
    return;
  }
  const float* xp = x + (size_t)(gy * 64 + gx) * 768;
  float v0 = xp[tid], v1 = xp[tid + 256], v2 = xp[tid + 512];
  float s = v0 + v1 + v2;
  float q = v0 * v0 + v1 * v1 + v2 * v2;
  #pragma unroll
  for (int off = 32; off; off >>= 1) { s += __shfl_xor(s, off); q += __shfl_xor(q, off); }
  __shared__ float red[8];
  int wid = tid >> 6, lane = tid & 63;
  if (lane == 0) { red[wid] = s; red[4 + wid] = q; }
  __syncthreads();
  s = red[0] + red[1] + red[2] + red[3];
  q = red[4] + red[5] + red[6] + red[7];
  float mean = s * (1.f / 768.f);
  float var  = q * (1.f / 768.f) - mean * mean;
  float rstd = rsqrtf(var + 1e-5f);
  yp[tid]       = f2bfu((v0 - mean) * rstd * bfu2f(g[tid])       + bfu2f(b[tid]));
  yp[tid + 256] = f2bfu((v1 - mean) * rstd * bfu2f(g[tid + 256]) + bfu2f(b[tid + 256]));
  yp[tid + 512] = f2bfu((v2 - mean) * rstd * bfu2f(g[tid + 512]) + bfu2f(b[tid + 512]));
}

// ---------------------------------------------------------------------------
enum { MODE_FEAT = 0, MODE_QKV = 1, MODE_RES = 2, MODE_GELU = 3, MODE_OUT = 4 };

// ---------------------------------------------------------------------------
// mgemm64_k: 64x64x64 tile GEMM, 4 waves (16x64 out each). XOR-swizzled LDS
// (blk^=row&7 on 16B blocks -> 2-way max on ds_read_b128) with pre-swizzled
// DMA sources; double-buffered; one barrier per 64-K. Direct-write epilogues.
// Requires M % 64 == 0, K % 64 == 0. Grid (N/64, M/64).
// ---------------------------------------------------------------------------
__global__ __launch_bounds__(256) void mgemm64_k(
    const u16* __restrict__ A, const u16* __restrict__ Bt, const u16* __restrict__ bias,
    int N, int K, int mode,
    float* __restrict__ outf, u16* __restrict__ outb,
    const float* __restrict__ res, const u16* __restrict__ pos,
    const int* __restrict__ flagp)
{
  __shared__ __align__(16) u16 As[2][64 * 64];
  __shared__ __align__(16) u16 Bs[2][64 * 64];
  const int tid = threadIdx.x;
  const int wid = tid >> 6, lane = tid & 63;
  const int l15 = lane & 15, quad = lane >> 4;
  const int m0 = blockIdx.y * 64, n0 = blockIdx.x * 64;

  auto swb = [](int row, int blk) { return row * 64 + (((blk ^ row) & 7) << 3); };

  floatx4 acc[4];
  #pragma unroll
  for (int ns = 0; ns < 4; ++ns) acc[ns] = (floatx4){0.f, 0.f, 0.f, 0.f};

  // DMA: each call = 8 rows x 64 u16 (lane: row = lane>>3, phys blk = lane&7).
  // Pre-swizzled source col so swizzled reads return correct data.
  const int srow = lane >> 3;
  const int scol = ((lane & 7) ^ srow) << 3;
  const u16* ap0 = A  + (size_t)(m0 + wid * 16 + srow) * K + scol;
  const u16* ap1 = ap0 + (size_t)8 * K;
  const u16* bp0 = Bt + (size_t)(n0 + wid * 16 + srow) * K + scol;
  const u16* bp1 = bp0 + (size_t)8 * K;

  auto issue = [&](int buf, int k0) {
    gld_lds16(ap0 + k0, &As[buf][(wid * 16) * 64]);
    gld_lds16(ap1 + k0, &As[buf][(wid * 16 + 8) * 64]);
    gld_lds16(bp0 + k0, &Bs[buf][(wid * 16) * 64]);
    gld_lds16(bp1 + k0, &Bs[buf][(wid * 16 + 8) * 64]);
  };

  issue(0, 0);
  int bufi = 0;
  for (int k0 = 0; k0 < K; k0 += 64, bufi ^= 1) {
    WAIT_VM0();                 // my DMA for buf bufi landed
    __syncthreads();            // all waves' DMA landed; prior reads done
    if (k0 + 64 < K) issue(bufi ^ 1, k0 + 64);
    short8 af[2], bf[4][2];
    af[0] = *(const short8*)&As[bufi][swb(wid * 16 + l15, quad)];
    af[1] = *(const short8*)&As[bufi][swb(wid * 16 + l15, 4 + quad)];
    #pragma unroll
    for (int ns = 0; ns < 4; ++ns) {
      bf[ns][0] = *(const short8*)&Bs[bufi][swb(ns * 16 + l15, quad)];
      bf[ns][1] = *(const short8*)&Bs[bufi][swb(ns * 16 + l15, 4 + quad)];
    }
    #pragma unroll
    for (int ns = 0; ns < 4; ++ns) {
      acc[ns] = __builtin_amdgcn_mfma_f32_16x16x32_bf16(af[0], bf[ns][0], acc[ns], 0, 0, 0);
      acc[ns] = __builtin_amdgcn_mfma_f32_16x16x32_bf16(af[1], bf[ns][1], acc[ns], 0, 0, 0);
    }
  }

  const bool outbf = (mode == MODE_OUT) ? (*flagp != 0) : false;
  const int gm0 = m0 + wid * 16 + quad * 4;
  #pragma unroll
  for (int ns = 0; ns < 4; ++ns) {
    const int gn = n0 + ns * 16 + l15;
    const float bb = bfu2f(bias[gn]);
    #pragma unroll
    for (int r = 0; r < 4; ++r) {
      const size_t o = (size_t)(gm0 + r) * N + gn;
      float v = acc[ns][r] + bb;
      if (mode == MODE_FEAT)      outf[o] = v + bfu2f(pos[o]);
      else if (mode == MODE_RES)  outf[o] = v + res[o];
      else {
        float ov = v + res[o];
        if (outbf) outb[o] = f2bfu(ov);
        else       outf[o] = ov;
      }
    }
  }
}

// ---------------------------------------------------------------------------
// MFMA GEMM (128xBN tile, BK=32), double-buffered global_load_lds staging.
// Used for QKV and GELU (BN=128).
// ---------------------------------------------------------------------------
template<int BN>
__global__ __launch_bounds__(256) void mgemm_k(
    const u16* __restrict__ A, const u16* __restrict__ Bt, const u16* __restrict__ bias,
    int M, int N, int K, int mode,
    u16* __restrict__ outb,
    u16* __restrict__ qb, u16* __restrict__ kb, u16* __restrict__ vt, int TW, int TP,
    const int* __restrict__ flagp)
{
  constexpr int NWN = BN / 64, NWM = 4 / NWN;
  constexpr int WTM = 128 / NWM;            // 64 or 32
  constexpr int MS = WTM / 16, NS = 4;
  __shared__ __align__(16) u16 As[2][128 * 32];
  __shared__ __align__(16) u16 Bs[2][BN * 32];
  const int tid = threadIdx.x;
  const int wid = tid >> 6, lane = tid & 63;
  const int l15 = lane & 15, quad = lane >> 4;
  const int wm = wid / NWN, wn = wid % NWN;
  const int m0 = blockIdx.y * 128, n0 = blockIdx.x * BN;

  floatx4 acc[MS][NS];
  #pragma unroll
  for (int i = 0; i < MS; ++i)
    #pragma unroll
    for (int j = 0; j < NS; ++j) acc[i][j] = (floatx4){0.f, 0.f, 0.f, 0.f};

  // staging: per wave, 16 rows per DMA call (lane>>2), 8 u16/lane ((lane&3)*8)
  const int sr = lane >> 2, sc = (lane & 3) * 8;
  const u16* ag0 = A + (size_t)min(m0 + wid * 32 + sr,      M - 1) * K + sc;
  const u16* ag1 = A + (size_t)min(m0 + wid * 32 + 16 + sr, M - 1) * K + sc;
  const u16 *bg0 = nullptr, *bg1 = nullptr;
  if constexpr (BN == 128) {
    bg0 = Bt + (size_t)(n0 + wid * 32 + sr) * K + sc;
    bg1 = Bt + (size_t)(n0 + wid * 32 + 16 + sr) * K + sc;
  } else {
    bg0 = Bt + (size_t)(n0 + wid * 16 + sr) * K + sc;
  }

  auto issue = [&](int buf, int k0) {
    gld_lds16(ag0 + k0, &As[buf][(wid * 32) * 32]);
    gld_lds16(ag1 + k0, &As[buf][(wid * 32 + 16) * 32]);
    if constexpr (BN == 128) {
      gld_lds16(bg0 + k0, &Bs[buf][(wid * 32) * 32]);
      gld_lds16(bg1 + k0, &Bs[buf][(wid * 32 + 16) * 32]);
    } else {
      gld_lds16(bg0 + k0, &Bs[buf][(wid * 16) * 32]);
    }
  };

  issue(0, 0);
  int bufi = 0;
  for (int k0 = 0; k0 < K; k0 += 32, bufi ^= 1) {
    WAIT_VM0();                 // my DMA for buf bufi landed
    __syncthreads();            // all waves' DMA landed; prior compute done
    if (k0 + 32 < K) issue(bufi ^ 1, k0 + 32);   // next tile flies during MFMAs
    short8 af[MS], bf[NS];
    #pragma unroll
    for (int ms = 0; ms < MS; ++ms)
      af[ms] = *(const short8*)&As[bufi][(wm * WTM + ms * 16 + l15) * 32 + quad * 8];
    #pragma unroll
    for (int ns = 0; ns < NS; ++ns)
      bf[ns] = *(const short8*)&Bs[bufi][(wn * 64 + ns * 16 + l15) * 32 + quad * 8];
    #pragma unroll
    for (int ms = 0; ms < MS; ++ms)
      #pragma unroll
      for (int ns = 0; ns < NS; ++ns)
        acc[ms][ns] = __builtin_amdgcn_mfma_f32_16x16x32_bf16(af[ms], bf[ns], acc[ms][ns], 0, 0, 0);
  }

  #pragma unroll
  for (int ms = 0; ms < MS; ++ms) {
    const int gmb = m0 + wm * WTM + ms * 16 + quad * 4;
    #pragma unroll
    for (int ns = 0; ns < NS; ++ns) {
      const int gn = n0 + wn * 64 + ns * 16 + l15;
      const float bb = bfu2f(bias[gn]);
      if (mode == MODE_QKV) {
        const int s = gn / 768, nn = gn - s * 768, h = nn >> 6, d = nn & 63;
        #pragma unroll
        for (int r = 0; r < 4; ++r) {
          int gm = gmb + r; if (gm >= M) continue;
          float v = acc[ms][ns][r] + bb;
          int b = gm / TW, tok = gm - b * TW;
          size_t bh = (size_t)(b * 12 + h);
          if (s == 0)      qb[(bh * TP + tok) * 64 + d] = f2bfu(v);
          else if (s == 1) kb[(bh * TP + tok) * 64 + d] = f2bfu(v);
          else             vt[(bh * 64 + d) * TP + tok] = f2bfu(v);
        }
      } else {  // MODE_GELU
        #pragma unroll
        for (int r = 0; r < 4; ++r) {
          int gm = gmb + r; if (gm >= M) continue;
          size_t o = (size_t)gm * N + gn;
          float v = acc[ms][ns][r] + bb;
          outb[o] = f2bfu(0.5f * v * (1.f + erff(v * 0.70710678f)));
        }
      }
    }
  }
}

// ---------------------------------------------------------------------------
// MFMA flash attention, swapped-operand (lane-local softmax rows).
// NT = logical tokens, NTP = padded stride (multiple of 64). Double-buffered
// global_load_lds K/V staging (pre-swizzled sources); K-loop unrolled x2 with
// literal dbuf bases. Padded keys masked via j<NT (WIN); padded V pre-zeroed.
// ---------------------------------------------------------------------------
template<int NT, int NTP, int TD, bool WIN>
__global__ __launch_bounds__(256) void flash_k(
    const u16* __restrict__ qb, const u16* __restrict__ kb, const u16* __restrict__ vt,
    const u16* __restrict__ relh, const u16* __restrict__ relw,
    u16* __restrict__ outb)
{
  constexpr int NTAB = 2 * TD - 1;
  constexpr int KT = NTP >> 6;
  constexpr float L2E = 1.4426950408889634f;
  constexpr float SC2 = 0.125f * L2E;
  // swizzled 64x64 u16 tile regions (4096 u16 each)
  constexpr int RQ  = 0;                          // Q stage -> P
  constexpr int RK0 = 4096;                       // K buf0; !WIN pre-loop: GW scratch
  constexpr int RK1 = 8192;                       // K buf1
  constexpr int RV0 = 12288;                      // V buf0; pre-loop: rel staging
  constexpr int RV1 = 16384;                      // V buf1
  constexpr int RG  = 20480;                      // GH table
  constexpr int GWWIN = RG + 64 * 34;
  constexpr int TOT = WIN ? (GWWIN + 64 * 34) : (RG + 64 * 66);
  __shared__ __align__(16) u16 lds[TOT];

  const int tid = threadIdx.x, wid = tid >> 6, lane = tid & 63;
  const int l15 = lane & 15, quad = lane >> 4;
  const int qt = blockIdx.x, bh = blockIdx.y;
  const int q0 = qt * 64;
  const size_t kvbase = (size_t)bh * NTP * 64;
  const size_t vbase  = (size_t)bh * 64 * NTP;
  const int myrow = wid * 16 + l15;               // this lane's q-row (lane-const)

  // u16 index of 16B block blk (0..7) in swizzled row
  auto swb = [](int row, int blk) { return row * 64 + (((blk ^ row) & 7) << 3); };

  // ---- stage Q tile (swizzled), hoist fragment to VGPRs ----
  {
    const int r = tid >> 2, cb = (tid & 3) * 2;
    const int tok = WIN ? (q0 + r) : min(q0 + r, NT - 1);
    const uint4* p = (const uint4*)(qb + kvbase + (size_t)tok * 64 + cb * 8);
    *(uint4*)&lds[RQ + swb(r, cb)]     = p[0];
    *(uint4*)&lds[RQ + swb(r, cb + 1)] = p[1];
  }
  __syncthreads();
  short8 qf[2];
  qf[0] = *(const short8*)&lds[RQ + swb(myrow, quad)];
  qf[1] = *(const short8*)&lds[RQ + swb(myrow, 4 + quad)];
  WAIT_LGKM0();   // Q reads done before anything (later P writes) touch RQ

  auto stageRB = [&](const u16* tab, int rowoff, int maxrow) {
    const int r = tid >> 2, cb = (tid & 3) * 2;
    const int tr = min(rowoff + r, maxrow);
    const uint4* p = (const uint4*)(tab + (size_t)tr * 64 + cb * 8);
    *(uint4*)&lds[RV0 + swb(r, cb)]     = p[0];
    *(uint4*)&lds[RV0 + swb(r, cb + 1)] = p[1];
  };
  auto gpass = [&](int gbase, int gstride, int ncols) {
    for (int ns = 0; ns < ncols / 16; ++ns) {
      floatx4 g = (floatx4){0.f, 0.f, 0.f, 0.f};
      #pragma unroll
      for (int ks = 0; ks < 2; ++ks) {
        short8 b = *(const short8*)&lds[RV0 + swb(ns * 16 + l15, ks * 4 + quad)];
        g = __builtin_amdgcn_mfma_f32_16x16x32_bf16(qf[ks], b, g, 0, 0, 0);
      }
      #pragma unroll
      for (int r = 0; r < 4; ++r)
        lds[gbase + (wid * 16 + quad * 4 + r) * gstride + ns * 16 + l15] = f2bfu(g[r] * L2E);
    }
  };

  // gwv[kbi][r]: GW bias for key = kbi*16 + quad*4 + r of this lane's row
  float gwv[4][4];
  if constexpr (!WIN) {
    stageRB(relh, qt, NTAB - 1);  __syncthreads();
    gpass(RG, 66, 64);                            // GH
    __syncthreads();                              // RV0 reads done -> restage ok
    stageRB(relw, 0, NTAB - 1);   __syncthreads();
    gpass(RK0, 66, 64);                           // GW cols 0..63 (scratch in K region)
    #pragma unroll
    for (int kbi = 0; kbi < 4; ++kbi)
      #pragma unroll
      for (int r = 0; r < 4; ++r) {
        const int iw = myrow + 63 - (kbi * 16 + quad * 4 + r);
        if (iw < 64) gwv[kbi][r] = bfu2f(lds[RK0 + myrow * 66 + iw]);
      }
    WAIT_LGKM0();
    __syncthreads();                              // scratch reads done -> restage ok
    stageRB(relw, 64, NTAB - 1);  __syncthreads();
    gpass(RK0, 66, 64);                           // GW cols 64..126 (stored 0..62)
    #pragma unroll
    for (int kbi = 0; kbi < 4; ++kbi)
      #pragma unroll
      for (int r = 0; r < 4; ++r) {
        const int iw = myrow + 63 - (kbi * 16 + quad * 4 + r);
        if (iw >= 64) gwv[kbi][r] = bfu2f(lds[RK0 + myrow * 66 + iw - 64]);
      }
    WAIT_LGKM0();   // GW reads done before DMA overwrites the K region
  } else {
    stageRB(relh, 0, NTAB - 1);  __syncthreads();
    gpass(RG, 34, 32);
    __syncthreads();
    stageRB(relw, 0, NTAB - 1);  __syncthreads();
    gpass(GWWIN, 34, 32);
  }

  // ---- double-buffered DMA staging, stepped pre-swizzled pointers ----
  const int srow = lane >> 3;
  const int scol = (((lane & 7) ^ srow) & 7) << 3;
  const u16* kp  = kb + kvbase + (size_t)(wid * 16 + srow) * 64 + scol;
  const u16* kp2 = kp + 512;                      // +8 key rows
  const u16* vp  = vt + vbase  + (size_t)(wid * 16 + srow) * NTP + scol;
  const u16* vp2 = vp + (size_t)8 * NTP;          // +8 d rows
  u16* const kd0 = &lds[RK0 + wid * 1024];
  u16* const kd1 = &lds[RK1 + wid * 1024];
  u16* const vd0 = &lds[RV0 + wid * 1024];
  u16* const vd1 = &lds[RV1 + wid * 1024];
  auto issueKV = [&](int buf) {
    u16* kdb = buf ? kd1 : kd0;
    u16* vdb = buf ? vd1 : vd0;
    gld_lds16(kp,  kdb);
    gld_lds16(kp2, kdb + 512);
    gld_lds16(vp,  vdb);
    gld_lds16(vp2, vdb + 512);
    kp += 4096; kp2 += 4096; vp += 64; vp2 += 64;
  };

  // ---- per-lane online-softmax state (row = myrow), exp2 domain ----
  float mI = -3e38f, lI = 0.f;
  floatx4 Oacc[4];                                // Oacc[dblk]: rows d, col = myrow
  #pragma unroll
  for (int d = 0; d < 4; ++d) Oacc[d] = (floatx4){0.f, 0.f, 0.f, 0.f};

  // WIN: per-lane q coords (lane-const)
  int qy = 0, qx = 0;
  if constexpr (WIN) {
    const int tok0 = q0 + myrow;
    qy = DIV14(tok0); qx = tok0 - 14 * qy;
  }

  // ---- shared per-tile body (inlined; bases literal at call sites) ----
  auto body = [&](int RKb, int RVb, int kt) {
    // QK^T swapped: C[key][q], lane col = myrow
    floatx4 sacc[4];
    #pragma unroll
    for (int kbi = 0; kbi < 4; ++kbi) sacc[kbi] = (floatx4){0.f, 0.f, 0.f, 0.f};
    __builtin_amdgcn_s_setprio(1);
    #pragma unroll
    for (int ks = 0; ks < 2; ++ks)
      #pragma unroll
      for (int kbi = 0; kbi < 4; ++kbi) {
        short8 a = *(const short8*)&lds[RKb + swb(kbi * 16 + l15, ks * 4 + quad)];
        sacc[kbi] = __builtin_amdgcn_mfma_f32_16x16x32_bf16(a, qf[ks], sacc[kbi], 0, 0, 0);
      }
    __builtin_amdgcn_s_setprio(0);

    // scale + rel bias (log2 units); sv[kbi][r] = score for key kbi*16+quad*4+r
    float sv[4][4];
    if constexpr (!WIN) {
      #pragma unroll
      for (int kbi = 0; kbi < 4; ++kbi)
        #pragma unroll
        for (int r = 0; r < 4; ++r)
          sv[kbi][r] = fmaf(SC2, sacc[kbi][r], gwv[kbi][r]);   // Gh folded below
    } else {
      #pragma unroll
      for (int kbi = 0; kbi < 4; ++kbi)
        #pragma unroll
        for (int r = 0; r < 4; ++r) {
          const int j = kt * 64 + kbi * 16 + quad * 4 + r;
          const int ky = DIV14(j), kx = j - 14 * ky;
          int ih = qy - ky + 13; ih = max(0, min(ih, 31));
          int iw = qx - kx + 13; iw = max(0, min(iw, 31));
          float s = SC2 * sacc[kbi][r] + bfu2f(lds[RG + myrow * 34 + ih])
                                       + bfu2f(lds[GWWIN + myrow * 34 + iw]);
          sv[kbi][r] = (j < NT) ? s : -1e30f;
        }
    }

    // row reduce: in-lane tree + 2 cross-quad shuffles
    float rm;
    {
      float a0 = fmaxf(fmaxf(sv[0][0], sv[0][1]), fmaxf(sv[0][2], sv[0][3]));
      float a1 = fmaxf(fmaxf(sv[1][0], sv[1][1]), fmaxf(sv[1][2], sv[1][3]));
      float a2 = fmaxf(fmaxf(sv[2][0], sv[2][1]), fmaxf(sv[2][2], sv[2][3]));
      float a3 = fmaxf(fmaxf(sv[3][0], sv[3][1]), fmaxf(sv[3][2], sv[3][3]));
      rm = fmaxf(fmaxf(a0, a1), fmaxf(a2, a3));
    }
    rm = fmaxf(rm, __shfl_xor(rm, 16));
    rm = fmaxf(rm, __shfl_xor(rm, 32));
    float ghv = 0.f;
    if constexpr (!WIN) ghv = bfu2f(lds[RG + myrow * 66 + (63 - kt)]);   // tile-const
    const float mt = rm + ghv;
    const float mn = fmaxf(mI, mt);
    const float tt = mn - ghv;

    float rs = 0.f;
    u32 pk[8];
    #pragma unroll
    for (int kbi = 0; kbi < 4; ++kbi) {
      float p0 = __builtin_amdgcn_exp2f(sv[kbi][0] - tt);
      float p1 = __builtin_amdgcn_exp2f(sv[kbi][1] - tt);
      float p2 = __builtin_amdgcn_exp2f(sv[kbi][2] - tt);
      float p3 = __builtin_amdgcn_exp2f(sv[kbi][3] - tt);
      rs += (p0 + p1) + (p2 + p3);
      pk[2 * kbi]     = cvtpk_bf16(p0, p1);
      pk[2 * kbi + 1] = cvtpk_bf16(p2, p3);
    }

    // write P: row myrow, cols kbi*16+quad*4 .. +3 (one b64 per kbi)
    #pragma unroll
    for (int kbi = 0; kbi < 4; ++kbi) {
      const int col = kbi * 16 + quad * 4;
      uint2 w2; w2.x = pk[2 * kbi]; w2.y = pk[2 * kbi + 1];
      *(uint2*)&lds[RQ + myrow * 64 + ((((col >> 3) ^ myrow) & 7) << 3) + (col & 7)] = w2;
    }

    // al == 1.0 exactly when no lane saw a new max -> lI update bit-exact
    const float al = __builtin_amdgcn_exp2f(mI - mn);
    if (__any(mt > mI)) {
      #pragma unroll
      for (int d = 0; d < 4; ++d) Oacc[d] *= al;
    }
    mI = mn;

    // PV swapped: A = V-frag (rows d), B = P-frag (col = myrow) -> O^T
    __builtin_amdgcn_s_setprio(1);
    #pragma unroll
    for (int ks = 0; ks < 2; ++ks) {
      short8 pb = *(const short8*)&lds[RQ + swb(myrow, ks * 4 + quad)];
      #pragma unroll
      for (int d = 0; d < 4; ++d) {
        short8 a = *(const short8*)&lds[RVb + swb(d * 16 + l15, ks * 4 + quad)];
        Oacc[d] = __builtin_amdgcn_mfma_f32_16x16x32_bf16(a, pb, Oacc[d], 0, 0, 0);
      }
    }
    __builtin_amdgcn_s_setprio(0);

    // rs cross-lane reduce hidden under PV MFMAs
    rs += __shfl_xor(rs, 16);
    rs += __shfl_xor(rs, 32);
    lI = fmaf(lI, al, rs);
  };

  // ---- K loop (KT even for both paths) ----
  __syncthreads();              // all waves done with pre-loop LDS scratch
  issueKV(0);                   // tile 0 -> buf0
  for (int kt = 0; kt < KT; kt += 2) {
    WAIT_VM0();                 // my DMA for tile kt landed
    __syncthreads();            // all waves' DMA landed; prior reads done
    if (kt + 1 < KT) issueKV(1);
    body(RK0, RV0, kt);
    WAIT_VM0();                 // my DMA for tile kt+1 landed
    __syncthreads();
    if (kt + 2 < KT) issueKV(0);
    body(RK1, RV1, kt + 1);
  }

  // ---- output: O^T rows d = dblk*16+quad*4+r, col = myrow (= token) ----
  const float rinv = 1.f / lI;
  const int tok = q0 + myrow;
  u32 ow[8];
  #pragma unroll
  for (int d = 0; d < 4; ++d) {
    ow[2 * d]     = cvtpk_bf16(Oacc[d][0] * rinv, Oacc[d][1] * rinv);
    ow[2 * d + 1] = cvtpk_bf16(Oacc[d][2] * rinv, Oacc[d][3] * rinv);
  }
  if constexpr (WIN) {
    if (tok < NT) {
      const int win = bh / 12, h = bh - win * 12;
      const int ty = DIV14(tok), tx = tok - 14 * ty;
      const int gy = (win / 5) * 14 + ty, gx = (win % 5) * 14 + tx;
      if (gy < 64 && gx < 64) {
        u16* op = outb + (size_t)(gy * 64 + gx) * 768 + h * 64;
        #pragma unroll
        for (int d = 0; d < 4; ++d)
          *(uint2*)(op + d * 16 + quad * 4) = make_uint2(ow[2 * d], ow[2 * d + 1]);
      }
    }
  } else {
    u16* op = outb + (size_t)tok * 768 + bh * 64;
    #pragma unroll
    for (int d = 0; d < 4; ++d)
      *(uint2*)(op + d * 16 + quad * 4) = make_uint2(ow[2 * d], ow[2 * d + 1]);
  }
}

// ---------------------------------------------------------------------------
extern "C" void kernel_launch(void* const* d_in, const int* in_sizes, int n_in,
                              void* d_out, int out_size, void* d_ws, size_t ws_size,
                              hipStream_t stream)
{
  const void* x      = d_in[0];
  const void* patchw = d_in[1];
  const void* patchb = d_in[2];
  const void* pos    = d_in[3];
  const void *ln1g1 = d_in[4],  *ln1b1 = d_in[5];
  const void *qkvw1 = d_in[6],  *qkvb1 = d_in[7];
  const void *projw1= d_in[8],  *projb1= d_in[9];
  const void *relh1 = d_in[10], *relw1 = d_in[11];
  const void *ln2g1 = d_in[12], *ln2b1 = d_in[13];
  const void *mw11  = d_in[14], *mb11  = d_in[15];
  const void *mw21  = d_in[16], *mb21  = d_in[17];
  const void *ln1g2 = d_in[18], *ln1b2 = d_in[19];
  const void *qkvw2 = d_in[20], *qkvb2 = d_in[21];
  const void *projw2= d_in[22], *projb2= d_in[23];
  const void *relh2 = d_in[24], *relw2 = d_in[25];
  const void *ln2g2 = d_in[26], *ln2b2 = d_in[27];
  const void *mw12  = d_in[28], *mb12  = d_in[29];
  const void *mw22  = d_in[30], *mb22  = d_in[31];

  char* w = (char*)d_ws;
  int*   FLAG = (int*)w;  w += 64;
  float* R0 = (float*)w;  w += 12582912;
  float* R1 = (float*)w;  w += 12582912;
  u16*   B0 = (u16*)w;    w += 6291456;
  u16*   Wb = (u16*)w;    w += 7526400;
  u16*   QB = (u16*)w;    w += 9830400;   // [bh][tok][64], padded tok stride
  u16*   KB = (u16*)w;    w += 9830400;   // [bh][tok][64]
  u16*   VT = (u16*)w;    w += 9830400;   // [bh][d][tok]
  u16*   Hb = (u16*)w;    w += 25165824;
  u16*   WA = (u16*)w;    w += 15335424;  // transposed weight arena (+patch slot)
  u16*   POSb = (u16*)w;  w += 6291456;
  u16*   PRM = (u16*)w;   w += 106560;
  u16*   Ap = Hb;

  constexpr int WA_QKV = 0, WA_PROJ = 1769472, WA_M1 = 2359296, WA_M2 = 4718592,
                WA_PATCH = 7077888;
  constexpr int PRM_PATCHB = 0, PB1 = 768, PBLK = 26240, PB2 = 768 + PBLK;
  constexpr int O_QKVB = 0, O_PROJB = 2304, O_MB1 = 3072, O_MB2 = 6144,
                O_LN1G = 6912, O_LN1B = 7680, O_LN2G = 8448, O_LN2B = 9216,
                O_RELH = 9984, O_RELW = 18112;

  detect_k<<<1, 256, 0, stream>>>((const u16*)x, FLAG);
  CvtArgs ca; int kk = 0;
  auto add = [&](const void* s, int n, int off) { ca.e[kk].src = s; ca.e[kk].n = n; ca.e[kk].dstoff = off; ++kk; };
  add(patchb, 768, PRM_PATCHB);
  add(qkvb1, 2304, PB1 + O_QKVB); add(projb1, 768, PB1 + O_PROJB);
  add(mb11, 3072, PB1 + O_MB1);   add(mb21, 768, PB1 + O_MB2);
  add(ln1g1, 768, PB1 + O_LN1G);  add(ln1b1, 768, PB1 + O_LN1B);
  add(ln2g1, 768, PB1 + O_LN2G);  add(ln2b1, 768, PB1 + O_LN2B);
  add(relh1, 27 * 64, PB1 + O_RELH); add(relw1, 27 * 64, PB1 + O_RELW);
  add(qkvb2, 2304, PB2 + O_QKVB); add(projb2, 768, PB2 + O_PROJB);
  add(mb12, 3072, PB2 + O_MB1);   add(mb22, 768, PB2 + O_MB2);
  add(ln1g2, 768, PB2 + O_LN1G);  add(ln1b2, 768, PB2 + O_LN1B);
  add(ln2g2, 768, PB2 + O_LN2G);  add(ln2b2, 768, PB2 + O_LN2B);
  add(relh2, 127 * 64, PB2 + O_RELH); add(relw2, 127 * 64, PB2 + O_RELW);
  ca.cnt = kk;
  tobf_multi_k<<<32, 256, 0, stream>>>(ca, PRM, FLAG);
  tobf4_k<<<3072, 256, 0, stream>>>(pos, POSb, 786432, FLAG);

  // ---- fused weight transposes: set 1 (patch + block 1) ----
  {
    TArgs ta; int nb = 0, jn = 0;
    auto addT = [&](const void* s, int dstoff, int K, int N) {
      ta.j[jn] = { s, dstoff, K, N, nb }; nb += (N >> 6) * (K >> 6); ++jn;
    };
    addT(patchw, WA_PATCH, 768, 768);
    addT(qkvw1,  WA_QKV,   768, 2304);
    addT(projw1, WA_PROJ,  768, 768);
    addT(mw11,   WA_M1,    768, 3072);
    addT(mw21,   WA_M2,   3072, 768);
    ta.njobs = jn;
    tobfT_multi_k<<<nb, 256, 0, stream>>>(ta, WA, FLAG);
  }

  // ---- patch embed ----
  im2col_k<<<4096, 256, 0, stream>>>(x, Ap, FLAG);
  mgemm64_k<<<dim3(12, 64), 256, 0, stream>>>(Ap, WA + WA_PATCH, PRM + PRM_PATCHB,
      768, 768, MODE_FEAT, R0, nullptr, nullptr, POSb, FLAG);

  // ---- block 1 (windowed) ----
  ln_win_k<<<4900, 256, 0, stream>>>(R0, PRM + PB1 + O_LN1G, PRM + PB1 + O_LN1B, Wb);
  hipMemsetAsync(VT, 0, 9830400, stream);   // padded V cols must be 0 (NaN guard)
  mgemm_k<128><<<dim3(18, 39), 256, 0, stream>>>(Wb, WA + WA_QKV, PRM + PB1 + O_QKVB,
      4900, 2304, 768, MODE_QKV, nullptr, QB, KB, VT, 196, 256, FLAG);
  flash_k<196, 256, 14, true><<<dim3(4, 300), 256, 0, stream>>>(QB, KB, VT,
      PRM + PB1 + O_RELH, PRM + PB1 + O_RELW, B0);
  mgemm64_k<<<dim3(12, 64), 256, 0, stream>>>(B0, WA + WA_PROJ, PRM + PB1 + O_PROJB,
      768, 768, MODE_RES, R1, nullptr, R0, nullptr, FLAG);
  ln_k<<<4096, 256, 0, stream>>>(R1, PRM + PB1 + O_LN2G, PRM + PB1 + O_LN2B, B0);
  mgemm_k<128><<<dim3(24, 32), 256, 0, stream>>>(B0, WA + WA_M1, PRM + PB1 + O_MB1,
      4096, 3072, 768, MODE_GELU, Hb, nullptr, nullptr, nullptr, 0, 0, FLAG);
  mgemm64_k<<<dim3(12, 64), 256, 0, stream>>>(Hb, WA + WA_M2, PRM + PB1 + O_MB2,
      768, 3072, MODE_RES, R0, nullptr, R1, nullptr, FLAG);

  // ---- fused weight transposes: set 2 (block 2) ----
  {
    TArgs ta; int nb = 0, jn = 0;
    auto addT = [&](const void* s, int dstoff, int K, int N) {
      ta.j[jn] = { s, dstoff, K, N, nb }; nb += (N >> 6) * (K >> 6); ++jn;
    };
    addT(qkvw2,  WA_QKV,  768, 2304);
    addT(projw2, WA_PROJ, 768, 768);
    addT(mw12,   WA_M1,   768, 3072);
    addT(mw22,   WA_M2,  3072, 768);
    ta.njobs = jn;
    tobfT_multi_k<<<nb, 256, 0, stream>>>(ta, WA, FLAG);
  }

  // ---- block 2 (global) ----
  ln_k<<<4096, 256, 0, stream>>>(R0, PRM + PB2 + O_LN1G, PRM + PB2 + O_LN1B, B0);
  mgemm_k<128><<<dim3(18, 32), 256, 0, stream>>>(B0, WA + WA_QKV, PRM + PB2 + O_QKVB,
      4096, 2304, 768, MODE_QKV, nullptr, QB, KB, VT, 4096, 4096, FLAG);
  flash_k<4096, 4096, 64, false><<<dim3(64, 12), 256, 0, stream>>>(QB, KB, VT,
      PRM + PB2 + O_RELH, PRM + PB2 + O_RELW, B0);
  mgemm64_k<<<dim3(12, 64), 256, 0, stream>>>(B0, WA + WA_PROJ, PRM + PB2 + O_PROJB,
      768, 768, MODE_RES, R1, nullptr, R0, nullptr, FLAG);
  ln_k<<<4096, 256, 0, stream>>>(R1, PRM + PB2 + O_LN2G, PRM + PB2 + O_LN2B, B0);
  mgemm_k<128><<<dim3(24, 32), 256, 0, stream>>>(B0, WA + WA_M1, PRM + PB2 + O_MB1,
      4096, 3072, 768, MODE_GELU, Hb, nullptr, nullptr, nullptr, 0, 0, FLAG);
  mgemm64_k<<<dim3(12, 64), 256, 0, stream>>>(Hb, WA + WA_M2, PRM + PB2 + O_MB2,
      768, 3072, MODE_OUT, (float*)d_out, (u16*)d_out, R1, nullptr, FLAG);
}